// Round 1
// baseline (629.050 us; speedup 1.0000x reference)
//
#include <hip/hip_runtime.h>
#include <hip/hip_fp16.h>

#define NN 100000     // num nodes
#define NE 1600000    // num edges
#define NEL 200000    // link-pred edges
#define TM 64         // nodes per block in k_hw1
#define TM2 128       // nodes per block in k_hw2

// Bucketed CSR build (R12 config — best measured): bucket = dst >> 9.
#define NBUCK 196     // ceil(NN/512)
#define CAPB  10240   // per-bucket capacity (mean 8163, sigma ~90)
#define TPE   8192    // edges per k_part block (196 blocks)

// ---------------- CSR build, pass A: partition edges into buckets ----------
__global__ __launch_bounds__(256) void k_part(const int* __restrict__ src,
                                              const int* __restrict__ dst,
                                              int* __restrict__ gcur,
                                              int* __restrict__ part) {
    __shared__ int hist[NBUCK];
    __shared__ int base[NBUCK];
    __shared__ int rk[NBUCK];
    int tid = threadIdx.x;
    for (int i = tid; i < NBUCK; i += 256) { hist[i] = 0; rk[i] = 0; }
    __syncthreads();
    int e0 = blockIdx.x * TPE;
    int e1 = min(e0 + TPE, NE);
    for (int e = e0 + tid; e < e1; e += 256)
        atomicAdd(&hist[dst[e] >> 9], 1);
    __syncthreads();
    for (int i = tid; i < NBUCK; i += 256)
        base[i] = i * CAPB + atomicAdd(&gcur[i], hist[i]);
    __syncthreads();
    for (int e = e0 + tid; e < e1; e += 256) {
        int d = dst[e];
        int s = src[e];
        int b = d >> 9;
        int r = atomicAdd(&rk[b], 1);
        part[base[b] + r] = ((d & 511) << 17) | s;   // src < 2^17
    }
}

// ---------------- CSR build, pass B: per-bucket LDS sort (prefix fused) ----
__global__ __launch_bounds__(256) void k_build(const int* __restrict__ gcur,
                                               const int* __restrict__ part,
                                               int* __restrict__ csr,
                                               int* __restrict__ off,
                                               float* __restrict__ dinv) {
    __shared__ int cnts[256];
    __shared__ int hist[512];
    __shared__ int loff[512];
    __shared__ int ssum[256];
    __shared__ int csrbuf[CAPB];
    int b = blockIdx.x;
    int tid = threadIdx.x;
    cnts[tid] = (tid < NBUCK) ? gcur[tid] : 0;       // inline bucket prefix
    __syncthreads();
    for (int st = 1; st < 256; st <<= 1) {
        int tmp = (tid >= st) ? cnts[tid - st] : 0;
        __syncthreads();
        cnts[tid] += tmp;
        __syncthreads();
    }
    int obase = (b == 0) ? 0 : cnts[b - 1];
    int cnt = gcur[b];
    int pbase = b * CAPB;
    hist[tid] = 0; hist[tid + 256] = 0;
    __syncthreads();
    for (int i = tid; i < cnt; i += 256)
        atomicAdd(&hist[part[pbase + i] >> 17], 1);
    __syncthreads();
    int a0 = hist[2 * tid], a1 = hist[2 * tid + 1];
    int pairs = a0 + a1;
    ssum[tid] = pairs;
    __syncthreads();
    for (int st = 1; st < 256; st <<= 1) {
        int tmp = (tid >= st) ? ssum[tid - st] : 0;
        __syncthreads();
        ssum[tid] += tmp;
        __syncthreads();
    }
    int pexcl = ssum[tid] - pairs;
    loff[2 * tid] = pexcl;
    loff[2 * tid + 1] = pexcl + a0;
    __syncthreads();
    for (int i = tid; i < 512; i += 256) {
        int d = b * 512 + i;
        if (d < NN) {
            int c = hist[i];
            off[d] = obase + loff[i] + c;            // end of row d
            dinv[d] = rsqrtf((float)(c + 1));        // +1 self-loop
        }
    }
    hist[tid] = 0; hist[tid + 256] = 0;              // reuse as rank counters
    __syncthreads();
    for (int i = tid; i < cnt; i += 256) {
        int rec = part[pbase + i];
        int dl = rec >> 17;
        int r = atomicAdd(&hist[dl], 1);
        csrbuf[loff[dl] + r] = rec & 0x1FFFF;
    }
    __syncthreads();
    for (int i = tid; i < cnt; i += 256)             // coalesced flush
        csr[obase + i] = csrbuf[i];
}

// ---------------- hw1' = dinv * ([x|pos] @ W1)  (80 -> 64), fp16 out -------
__global__ __launch_bounds__(256) void k_hw1(const float* __restrict__ x,
                                             const float* __restrict__ pos,
                                             const float* __restrict__ W1,
                                             const float* __restrict__ dinv,
                                             __half* __restrict__ hw1) {
    __shared__ float sh[TM * 80];
    __shared__ float sw[80 * 64];
    int tid = threadIdx.x;
    for (int t = tid; t < 80 * 64; t += 256) sw[t] = W1[t];
    int nb = blockIdx.x * TM;
    for (int i = tid; i < TM * 64; i += 256) {
        int node = i >> 6, ch = i & 63;
        int g = nb + node;
        sh[node * 80 + ch] = (g < NN) ? x[g * 64 + ch] : 0.0f;
    }
    for (int i = tid; i < TM * 16; i += 256) {
        int node = i >> 4, ch = i & 15;
        int g = nb + node;
        sh[node * 80 + 64 + ch] = (g < NN) ? pos[g * 16 + ch] : 0.0f;
    }
    __syncthreads();
    int j  = (tid & 15) * 4;
    int nl = (tid >> 4) * 4;
    float a00=0,a01=0,a02=0,a03=0, a10=0,a11=0,a12=0,a13=0;
    float a20=0,a21=0,a22=0,a23=0, a30=0,a31=0,a32=0,a33=0;
#pragma unroll 4
    for (int k = 0; k < 80; ++k) {
        float4 wv = *(const float4*)&sw[k * 64 + j];
        float h0 = sh[(nl + 0) * 80 + k];
        float h1 = sh[(nl + 1) * 80 + k];
        float h2 = sh[(nl + 2) * 80 + k];
        float h3 = sh[(nl + 3) * 80 + k];
        a00 += h0 * wv.x; a01 += h0 * wv.y; a02 += h0 * wv.z; a03 += h0 * wv.w;
        a10 += h1 * wv.x; a11 += h1 * wv.y; a12 += h1 * wv.z; a13 += h1 * wv.w;
        a20 += h2 * wv.x; a21 += h2 * wv.y; a22 += h2 * wv.z; a23 += h2 * wv.w;
        a30 += h3 * wv.x; a31 += h3 * wv.y; a32 += h3 * wv.z; a33 += h3 * wv.w;
    }
    int g0 = nb + nl;
    union { __half2 h2v[2]; float2 f2; } u;
#define STORE_ROW(r, b0, b1, b2, b3)                                          \
    if (g0 + r < NN) {                                                        \
        float sc = dinv[g0 + r];                                              \
        u.h2v[0] = __floats2half2_rn(b0 * sc, b1 * sc);                       \
        u.h2v[1] = __floats2half2_rn(b2 * sc, b3 * sc);                       \
        *(float2*)&hw1[(g0 + r) * 64 + j] = u.f2;                             \
    }
    STORE_ROW(0, a00, a01, a02, a03)
    STORE_ROW(1, a10, a11, a12, a13)
    STORE_ROW(2, a20, a21, a22, a23)
    STORE_ROW(3, a30, a31, a32, a33)
#undef STORE_ROW
}

// ---------------- layer-1 gather (R16: 4 rows per load, 32 edges in flight)
// h2[d][c] = relu(b1[c] + dinv[d] * (sum_e hw1'[s] + hw1'[d]))
// Lane = (quarter q, chan-group cl): loads dwordx2 = 4 channels of row for
// edge e+4k+q. csr indices come from uniform s_loads (e is SGPR), selected
// by 3 cndmask. Masked lanes clamp to row d (L1-hot line, no extra fetch)
// and contribute 0 via fmaf mask. Quarters combined by 2 butterfly shuffles.
// R15 channel-slicing regressed 3.2x (sector granularity) — do not re-slice.
__global__ __launch_bounds__(256) void k_gather1(const int* __restrict__ off,
                                                 const int* __restrict__ csr,
                                                 const float* __restrict__ dinv,
                                                 const __half* __restrict__ hw,
                                                 const float* __restrict__ b1,
                                                 __half* __restrict__ h2out) {
    int lane = threadIdx.x & 63;
    int q  = lane >> 4;                        // edge-in-group-of-4
    int cl = lane & 15;                        // channels 4cl..4cl+3
    int wave = threadIdx.x >> 6;
    int d = blockIdx.x * 4 + wave;             // grid = NN/4 exactly
    int start = (d == 0) ? 0 : off[d - 1];
    int end = off[d];
    start = __builtin_amdgcn_readfirstlane(start);   // SGPR bounds ->
    end   = __builtin_amdgcn_readfirstlane(end);     // scalar csr loads
    float dd = dinv[d];
    uint2 selfbits = *(const uint2*)&hw[d * 64 + 4 * cl];  // hoisted self row
    float4 acc = make_float4(0.f, 0.f, 0.f, 0.f);
    for (int e = start; e < end; e += 32) {
        int sv[32];
#pragma unroll
        for (int j = 0; j < 32; ++j) sv[j] = csr[e + j];   // s_load_dwordx16
        int srow[8]; float msk[8];
#pragma unroll
        for (int k = 0; k < 8; ++k) {
            int s01 = (q & 1) ? sv[4 * k + 1] : sv[4 * k + 0];
            int s23 = (q & 1) ? sv[4 * k + 3] : sv[4 * k + 2];
            int s   = (q & 2) ? s23 : s01;
            int rem = end - e - 4 * k;         // SALU
            bool valid = q < rem;
            srow[k] = valid ? s : d;           // clamp to hot self-row line
            msk[k]  = valid ? 1.0f : 0.0f;
        }
        uint2 g[8];
#pragma unroll
        for (int k = 0; k < 8; ++k)            // 8 x 512B rows-in-flight
            g[k] = *(const uint2*)&hw[srow[k] * 64 + 4 * cl];
#pragma unroll
        for (int k = 0; k < 8; ++k) {
            float2 lo = __half22float2(*(__half2*)&g[k].x);
            float2 hi = __half22float2(*(__half2*)&g[k].y);
            acc.x = fmaf(msk[k], lo.x, acc.x);
            acc.y = fmaf(msk[k], lo.y, acc.y);
            acc.z = fmaf(msk[k], hi.x, acc.z);
            acc.w = fmaf(msk[k], hi.y, acc.w);
        }
    }
    acc.x += __shfl_xor(acc.x, 16, 64);        // combine quarters
    acc.y += __shfl_xor(acc.y, 16, 64);
    acc.z += __shfl_xor(acc.z, 16, 64);
    acc.w += __shfl_xor(acc.w, 16, 64);
    acc.x += __shfl_xor(acc.x, 32, 64);
    acc.y += __shfl_xor(acc.y, 32, 64);
    acc.z += __shfl_xor(acc.z, 32, 64);
    acc.w += __shfl_xor(acc.w, 32, 64);
    if (q == 0) {
        float2 slo = __half22float2(*(__half2*)&selfbits.x);
        float2 shi = __half22float2(*(__half2*)&selfbits.y);
        float4 bv = *(const float4*)&b1[4 * cl];
        float v0 = fmaxf(bv.x + dd * (acc.x + slo.x), 0.0f);
        float v1 = fmaxf(bv.y + dd * (acc.y + slo.y), 0.0f);
        float v2 = fmaxf(bv.z + dd * (acc.z + shi.x), 0.0f);
        float v3 = fmaxf(bv.w + dd * (acc.w + shi.y), 0.0f);
        union { __half2 h[2]; float2 f; } u;
        u.h[0] = __floats2half2_rn(v0, v1);
        u.h[1] = __floats2half2_rn(v2, v3);
        *(float2*)&h2out[d * 64 + 4 * cl] = u.f;
    }
}

// ---------------- hw2' = dinv * (h2 @ W2)  (64 -> 32), fp16 in/out ---------
__global__ __launch_bounds__(256) void k_hw2(const __half* __restrict__ h2,
                                             const float* __restrict__ W2,
                                             const float* __restrict__ dinv,
                                             __half* __restrict__ hw2) {
    __shared__ float sh[TM2 * 65];  // [node][feat], stride 65 (pad)
    __shared__ float sw[64 * 32];
    int tid = threadIdx.x;
    for (int t = tid; t < 64 * 32; t += 256) sw[t] = W2[t];
    int nb = blockIdx.x * TM2;
    for (int i = tid; i < TM2 * 64; i += 256) {
        int node = i >> 6, ch = i & 63;
        int g = nb + node;
        sh[node * 65 + ch] = (g < NN) ? __half2float(h2[g * 64 + ch]) : 0.0f;
    }
    __syncthreads();
    int j  = (tid & 7) * 4;
    int nl = (tid >> 3) * 4;
    float a00=0,a01=0,a02=0,a03=0, a10=0,a11=0,a12=0,a13=0;
    float a20=0,a21=0,a22=0,a23=0, a30=0,a31=0,a32=0,a33=0;
#pragma unroll 4
    for (int k = 0; k < 64; ++k) {
        float4 wv = *(const float4*)&sw[k * 32 + j];
        float h0 = sh[(nl + 0) * 65 + k];
        float h1 = sh[(nl + 1) * 65 + k];
        float h2v = sh[(nl + 2) * 65 + k];
        float h3 = sh[(nl + 3) * 65 + k];
        a00 += h0 * wv.x;  a01 += h0 * wv.y;  a02 += h0 * wv.z;  a03 += h0 * wv.w;
        a10 += h1 * wv.x;  a11 += h1 * wv.y;  a12 += h1 * wv.z;  a13 += h1 * wv.w;
        a20 += h2v * wv.x; a21 += h2v * wv.y; a22 += h2v * wv.z; a23 += h2v * wv.w;
        a30 += h3 * wv.x;  a31 += h3 * wv.y;  a32 += h3 * wv.z;  a33 += h3 * wv.w;
    }
    int g0 = nb + nl;
    union { __half2 h2v2[2]; float2 f2; } u;
#define STORE_ROW(r, b0, b1, b2, b3)                                          \
    if (g0 + r < NN) {                                                        \
        float sc = dinv[g0 + r];                                              \
        u.h2v2[0] = __floats2half2_rn(b0 * sc, b1 * sc);                      \
        u.h2v2[1] = __floats2half2_rn(b2 * sc, b3 * sc);                      \
        *(float2*)&hw2[(g0 + r) * 32 + j] = u.f2;                            \
    }
    STORE_ROW(0, a00, a01, a02, a03)
    STORE_ROW(1, a10, a11, a12, a13)
    STORE_ROW(2, a20, a21, a22, a23)
    STORE_ROW(3, a30, a31, a32, a33)
#undef STORE_ROW
}

// ---------------- layer-2 gather (R16: 8 rows per load, 32 edges in flight)
// z[d][j] = b2[j] + dinv[d] * (sum_e hw2'[s] + hw2'[d])
// Also emits per-node link-pred dots: u[d] = z[d]·Wl[0:32], v[d] = z[d]·Wl[32:64]
__global__ __launch_bounds__(256) void k_gather2(const int* __restrict__ off,
                                                 const int* __restrict__ csr,
                                                 const float* __restrict__ dinv,
                                                 const __half* __restrict__ hw,
                                                 const float* __restrict__ b2,
                                                 const float* __restrict__ Wl,
                                                 float* __restrict__ outz,
                                                 float* __restrict__ uu,
                                                 float* __restrict__ vv) {
    int lane = threadIdx.x & 63;
    int g8 = lane >> 3;                        // edge-in-group-of-8
    int cl = lane & 7;                         // channels 4cl..4cl+3
    int wave = threadIdx.x >> 6;
    int d = blockIdx.x * 4 + wave;             // grid = NN/4 exactly
    int start = (d == 0) ? 0 : off[d - 1];
    int end = off[d];
    start = __builtin_amdgcn_readfirstlane(start);
    end   = __builtin_amdgcn_readfirstlane(end);
    float dd = dinv[d];
    uint2 selfbits = *(const uint2*)&hw[d * 32 + 4 * cl];
    float4 acc = make_float4(0.f, 0.f, 0.f, 0.f);
    for (int e = start; e < end; e += 32) {
        int sv[32];
#pragma unroll
        for (int j = 0; j < 32; ++j) sv[j] = csr[e + j];   // s_load_dwordx16
        int srow[4]; float msk[4];
#pragma unroll
        for (int k = 0; k < 4; ++k) {
            int t0 = (g8 & 1) ? sv[8 * k + 1] : sv[8 * k + 0];
            int t1 = (g8 & 1) ? sv[8 * k + 3] : sv[8 * k + 2];
            int t2 = (g8 & 1) ? sv[8 * k + 5] : sv[8 * k + 4];
            int t3 = (g8 & 1) ? sv[8 * k + 7] : sv[8 * k + 6];
            int u0 = (g8 & 2) ? t1 : t0;
            int u1 = (g8 & 2) ? t3 : t2;
            int s  = (g8 & 4) ? u1 : u0;
            int rem = end - e - 8 * k;
            bool valid = g8 < rem;
            srow[k] = valid ? s : d;
            msk[k]  = valid ? 1.0f : 0.0f;
        }
        uint2 g[4];
#pragma unroll
        for (int k = 0; k < 4; ++k)            // 4 x 512B = 32 rows-in-flight
            g[k] = *(const uint2*)&hw[srow[k] * 32 + 4 * cl];
#pragma unroll
        for (int k = 0; k < 4; ++k) {
            float2 lo = __half22float2(*(__half2*)&g[k].x);
            float2 hi = __half22float2(*(__half2*)&g[k].y);
            acc.x = fmaf(msk[k], lo.x, acc.x);
            acc.y = fmaf(msk[k], lo.y, acc.y);
            acc.z = fmaf(msk[k], hi.x, acc.z);
            acc.w = fmaf(msk[k], hi.y, acc.w);
        }
    }
#pragma unroll
    for (int m = 8; m <= 32; m <<= 1) {        // combine 8 edge-groups
        acc.x += __shfl_xor(acc.x, m, 64);
        acc.y += __shfl_xor(acc.y, m, 64);
        acc.z += __shfl_xor(acc.z, m, 64);
        acc.w += __shfl_xor(acc.w, m, 64);
    }
    if (g8 == 0) {                             // lanes 0..7 hold the z row
        float2 slo = __half22float2(*(__half2*)&selfbits.x);
        float2 shi = __half22float2(*(__half2*)&selfbits.y);
        float4 bv = *(const float4*)&b2[4 * cl];
        float4 z;
        z.x = bv.x + dd * (acc.x + slo.x);
        z.y = bv.y + dd * (acc.y + slo.y);
        z.z = bv.z + dd * (acc.z + shi.x);
        z.w = bv.w + dd * (acc.w + shi.y);
        *(float4*)&outz[d * 32 + 4 * cl] = z;
        float4 ws = *(const float4*)&Wl[4 * cl];
        float4 wd = *(const float4*)&Wl[32 + 4 * cl];
        float p0 = z.x * ws.x + z.y * ws.y + z.z * ws.z + z.w * ws.w;
        float p1 = z.x * wd.x + z.y * wd.y + z.z * wd.z + z.w * wd.w;
        p0 += __shfl_xor(p0, 1, 64); p1 += __shfl_xor(p1, 1, 64);
        p0 += __shfl_xor(p0, 2, 64); p1 += __shfl_xor(p1, 2, 64);
        p0 += __shfl_xor(p0, 4, 64); p1 += __shfl_xor(p1, 4, 64);
        if (cl == 0) { uu[d] = p0; vv[d] = p1; }
    }
}

// ---------------- link prediction head: pred = u[s] + v[d] + bl ------------
// u,v precomputed in k_gather2 (800 KB, L2-resident) — replaces 2x128B
// random z-row gathers per edge (~51 MB fetch) with 2x4B lookups.
__global__ __launch_bounds__(256) void k_linkpred(const int* __restrict__ sidx,
                                                  const int* __restrict__ didx,
                                                  const float* __restrict__ uu,
                                                  const float* __restrict__ vv,
                                                  const float* __restrict__ bl,
                                                  float* __restrict__ pred) {
    int e = blockIdx.x * 256 + threadIdx.x;
    if (e < NEL)
        pred[e] = uu[sidx[e]] + vv[didx[e]] + bl[0];
}

extern "C" void kernel_launch(void* const* d_in, const int* in_sizes, int n_in,
                              void* d_out, int out_size, void* d_ws, size_t ws_size,
                              hipStream_t stream) {
    const float* x    = (const float*)d_in[0];
    const float* pos  = (const float*)d_in[1];
    const float* W1   = (const float*)d_in[2];
    const float* b1   = (const float*)d_in[3];
    const float* W2   = (const float*)d_in[4];
    const float* b2   = (const float*)d_in[5];
    const float* Wl   = (const float*)d_in[6];
    const float* bl   = (const float*)d_in[7];
    const int*   ei   = (const int*)d_in[8];   // [2, NE]
    const int*   eli  = (const int*)d_in[9];   // [2, NEL]
    const int* src  = ei;
    const int* dst  = ei + NE;
    const int* lsrc = eli;
    const int* ldst = eli + NEL;

    float* out_z    = (float*)d_out;            // [NN, 32]
    float* out_pred = (float*)d_out + NN * 32;  // [NEL]

    // workspace: dinv[NN]f | off[NN]i | gcur[NBUCK] | csr[NE]i |
    //            hw1'[NN*64]h (aliases part[NBUCK*CAPB]i = 8.0 MB, dead after
    //            k_build; also provides safe slack for csr[e..e+31] scalar
    //            over-reads) | h2[NN*64]h (dead after k_hw2 -> reused for
    //            uu/vv) | hw2'[NN*32]h   ~= 39.2 MB
    float*  dinv  = (float*)d_ws;
    int*    off   = (int*)(dinv + NN);
    int*    gcur  = off + NN;
    int*    csr   = gcur + NBUCK;
    __half* hw1   = (__half*)(csr + NE);
    int*    part  = (int*)hw1;                  // 8.0 MB <= hw1's 12.8 MB
    __half* h2    = hw1 + NN * 64;
    __half* hw2   = h2 + NN * 64;
    float*  uu    = (float*)h2;                 // h2 dead after k_hw2
    float*  vv    = uu + NN;

    // 1) CSR build: partition -> per-bucket LDS sort (prefix fused, +dinv)
    hipMemsetAsync(gcur, 0, NBUCK * sizeof(int), stream);
    k_part<<<(NE + TPE - 1) / TPE, 256, 0, stream>>>(src, dst, gcur, part);
    k_build<<<NBUCK, 256, 0, stream>>>(gcur, part, csr, off, dinv);

    // 2) hw1' = dinv * ([x|pos] @ W1), fp16  (overwrites part — now dead)
    k_hw1<<<(NN + TM - 1) / TM, 256, 0, stream>>>(x, pos, W1, dinv, hw1);

    // 3) layer-1 gather + bias + relu -> h2 (fp16), 32 edges in flight
    k_gather1<<<NN / 4, 256, 0, stream>>>(off, csr, dinv, hw1, b1, h2);

    // 4) hw2' = dinv * (h2 @ W2), fp16
    k_hw2<<<(NN + TM2 - 1) / TM2, 256, 0, stream>>>(h2, W2, dinv, hw2);

    // 5) layer-2 gather + bias -> z (fp32 out) + per-node linkpred dots u,v
    k_gather2<<<NN / 4, 256, 0, stream>>>(off, csr, dinv, hw2, b2, Wl,
                                          out_z, uu, vv);

    // 6) link prediction: pred[e] = u[s] + v[d] + bl
    k_linkpred<<<(NEL + 255) / 256, 256, 0, stream>>>(lsrc, ldst, uu, vv, bl,
                                                      out_pred);
}

// Round 2
// 306.423 us; speedup vs baseline: 2.0529x; 2.0529x over previous
//
#include <hip/hip_runtime.h>
#include <hip/hip_fp16.h>

#define NN 100000     // num nodes
#define NE 1600000    // num edges
#define NEL 200000    // link-pred edges
#define TM 64         // nodes per block in k_hw1
#define TM2 128       // nodes per block in k_hw2

// Bucketed CSR build (R12 config — best measured): bucket = dst >> 9.
#define NBUCK 196     // ceil(NN/512)
#define CAPB  10240   // per-bucket capacity (mean 8163, sigma ~90)
#define TPE   8192    // edges per k_part block (196 blocks)

// ---------------- CSR build, pass A: partition edges into buckets ----------
__global__ __launch_bounds__(256) void k_part(const int* __restrict__ src,
                                              const int* __restrict__ dst,
                                              int* __restrict__ gcur,
                                              int* __restrict__ part) {
    __shared__ int hist[NBUCK];
    __shared__ int base[NBUCK];
    __shared__ int rk[NBUCK];
    int tid = threadIdx.x;
    for (int i = tid; i < NBUCK; i += 256) { hist[i] = 0; rk[i] = 0; }
    __syncthreads();
    int e0 = blockIdx.x * TPE;
    int e1 = min(e0 + TPE, NE);
    for (int e = e0 + tid; e < e1; e += 256)
        atomicAdd(&hist[dst[e] >> 9], 1);
    __syncthreads();
    for (int i = tid; i < NBUCK; i += 256)
        base[i] = i * CAPB + atomicAdd(&gcur[i], hist[i]);
    __syncthreads();
    for (int e = e0 + tid; e < e1; e += 256) {
        int d = dst[e];
        int s = src[e];
        int b = d >> 9;
        int r = atomicAdd(&rk[b], 1);
        part[base[b] + r] = ((d & 511) << 17) | s;   // src < 2^17
    }
}

// ---------------- CSR build, pass B: per-bucket LDS sort (prefix fused) ----
__global__ __launch_bounds__(256) void k_build(const int* __restrict__ gcur,
                                               const int* __restrict__ part,
                                               int* __restrict__ csr,
                                               int* __restrict__ off,
                                               float* __restrict__ dinv) {
    __shared__ int cnts[256];
    __shared__ int hist[512];
    __shared__ int loff[512];
    __shared__ int ssum[256];
    __shared__ int csrbuf[CAPB];
    int b = blockIdx.x;
    int tid = threadIdx.x;
    cnts[tid] = (tid < NBUCK) ? gcur[tid] : 0;       // inline bucket prefix
    __syncthreads();
    for (int st = 1; st < 256; st <<= 1) {
        int tmp = (tid >= st) ? cnts[tid - st] : 0;
        __syncthreads();
        cnts[tid] += tmp;
        __syncthreads();
    }
    int obase = (b == 0) ? 0 : cnts[b - 1];
    int cnt = gcur[b];
    int pbase = b * CAPB;
    hist[tid] = 0; hist[tid + 256] = 0;
    __syncthreads();
    for (int i = tid; i < cnt; i += 256)
        atomicAdd(&hist[part[pbase + i] >> 17], 1);
    __syncthreads();
    int a0 = hist[2 * tid], a1 = hist[2 * tid + 1];
    int pairs = a0 + a1;
    ssum[tid] = pairs;
    __syncthreads();
    for (int st = 1; st < 256; st <<= 1) {
        int tmp = (tid >= st) ? ssum[tid - st] : 0;
        __syncthreads();
        ssum[tid] += tmp;
        __syncthreads();
    }
    int pexcl = ssum[tid] - pairs;
    loff[2 * tid] = pexcl;
    loff[2 * tid + 1] = pexcl + a0;
    __syncthreads();
    for (int i = tid; i < 512; i += 256) {
        int d = b * 512 + i;
        if (d < NN) {
            int c = hist[i];
            off[d] = obase + loff[i] + c;            // end of row d
            dinv[d] = rsqrtf((float)(c + 1));        // +1 self-loop
        }
    }
    hist[tid] = 0; hist[tid + 256] = 0;              // reuse as rank counters
    __syncthreads();
    for (int i = tid; i < cnt; i += 256) {
        int rec = part[pbase + i];
        int dl = rec >> 17;
        int r = atomicAdd(&hist[dl], 1);
        csrbuf[loff[dl] + r] = rec & 0x1FFFF;
    }
    __syncthreads();
    for (int i = tid; i < cnt; i += 256)             // coalesced flush
        csr[obase + i] = csrbuf[i];
}

// ---------------- hw1' = dinv * ([x|pos] @ W1)  (80 -> 64), fp16 out -------
__global__ __launch_bounds__(256) void k_hw1(const float* __restrict__ x,
                                             const float* __restrict__ pos,
                                             const float* __restrict__ W1,
                                             const float* __restrict__ dinv,
                                             __half* __restrict__ hw1) {
    __shared__ float sh[TM * 80];
    __shared__ float sw[80 * 64];
    int tid = threadIdx.x;
    for (int t = tid; t < 80 * 64; t += 256) sw[t] = W1[t];
    int nb = blockIdx.x * TM;
    for (int i = tid; i < TM * 64; i += 256) {
        int node = i >> 6, ch = i & 63;
        int g = nb + node;
        sh[node * 80 + ch] = (g < NN) ? x[g * 64 + ch] : 0.0f;
    }
    for (int i = tid; i < TM * 16; i += 256) {
        int node = i >> 4, ch = i & 15;
        int g = nb + node;
        sh[node * 80 + 64 + ch] = (g < NN) ? pos[g * 16 + ch] : 0.0f;
    }
    __syncthreads();
    int j  = (tid & 15) * 4;
    int nl = (tid >> 4) * 4;
    float a00=0,a01=0,a02=0,a03=0, a10=0,a11=0,a12=0,a13=0;
    float a20=0,a21=0,a22=0,a23=0, a30=0,a31=0,a32=0,a33=0;
#pragma unroll 4
    for (int k = 0; k < 80; ++k) {
        float4 wv = *(const float4*)&sw[k * 64 + j];
        float h0 = sh[(nl + 0) * 80 + k];
        float h1 = sh[(nl + 1) * 80 + k];
        float h2 = sh[(nl + 2) * 80 + k];
        float h3 = sh[(nl + 3) * 80 + k];
        a00 += h0 * wv.x; a01 += h0 * wv.y; a02 += h0 * wv.z; a03 += h0 * wv.w;
        a10 += h1 * wv.x; a11 += h1 * wv.y; a12 += h1 * wv.z; a13 += h1 * wv.w;
        a20 += h2 * wv.x; a21 += h2 * wv.y; a22 += h2 * wv.z; a23 += h2 * wv.w;
        a30 += h3 * wv.x; a31 += h3 * wv.y; a32 += h3 * wv.z; a33 += h3 * wv.w;
    }
    int g0 = nb + nl;
    union { __half2 h2v[2]; float2 f2; } u;
#define STORE_ROW(r, b0, b1, b2, b3)                                          \
    if (g0 + r < NN) {                                                        \
        float sc = dinv[g0 + r];                                              \
        u.h2v[0] = __floats2half2_rn(b0 * sc, b1 * sc);                       \
        u.h2v[1] = __floats2half2_rn(b2 * sc, b3 * sc);                       \
        *(float2*)&hw1[(g0 + r) * 64 + j] = u.f2;                             \
    }
    STORE_ROW(0, a00, a01, a02, a03)
    STORE_ROW(1, a10, a11, a12, a13)
    STORE_ROW(2, a20, a21, a22, a23)
    STORE_ROW(3, a30, a31, a32, a33)
#undef STORE_ROW
}

// ---------------- layer-1 gather (R12 version: 54.4 us measured) -----------
// h2[d][c] = relu(b1[c] + dinv[d] * (sum_e hw1'[s] + hw1'[d]))
// Full 64-lane rows, shuffle-free edge loop, 8 outstanding 128B gathers.
// R15 channel-slicing regressed 3.2x (sector granularity) — do not re-slice.
// R16 batched-index restructure regressed 5x (scratch spill, WRITE 814MB) —
// do not batch csr indices into arrays.
__global__ __launch_bounds__(256) void k_gather1(const int* __restrict__ off,
                                                 const int* __restrict__ csr,
                                                 const float* __restrict__ dinv,
                                                 const __half* __restrict__ hw,
                                                 const float* __restrict__ b1,
                                                 __half* __restrict__ h2out) {
    int lane = threadIdx.x & 63;
    int wave = threadIdx.x >> 6;
    int d = blockIdx.x * 4 + wave;             // grid = NN/4 exactly
    int start = (d == 0) ? 0 : off[d - 1];
    int end = off[d];
    start = __builtin_amdgcn_readfirstlane(start);   // SGPR bounds ->
    end   = __builtin_amdgcn_readfirstlane(end);     // scalar csr loads
    float dd = dinv[d];
    float hself = __half2float(hw[d * 64 + lane]);   // hoisted
    float acc0 = 0.0f, acc1 = 0.0f, acc2 = 0.0f, acc3 = 0.0f;
    int e = start;
    for (; e + 7 < end; e += 8) {              // 8 outstanding gathers
        int s0 = csr[e],     s1 = csr[e + 1];
        int s2 = csr[e + 2], s3 = csr[e + 3];
        int s4 = csr[e + 4], s5 = csr[e + 5];
        int s6 = csr[e + 6], s7 = csr[e + 7];
        float g0 = __half2float(hw[s0 * 64 + lane]);
        float g1 = __half2float(hw[s1 * 64 + lane]);
        float g2 = __half2float(hw[s2 * 64 + lane]);
        float g3 = __half2float(hw[s3 * 64 + lane]);
        float g4 = __half2float(hw[s4 * 64 + lane]);
        float g5 = __half2float(hw[s5 * 64 + lane]);
        float g6 = __half2float(hw[s6 * 64 + lane]);
        float g7 = __half2float(hw[s7 * 64 + lane]);
        acc0 += g0; acc1 += g1; acc2 += g2; acc3 += g3;
        acc0 += g4; acc1 += g5; acc2 += g6; acc3 += g7;
    }
    for (; e < end; ++e)                       // uniform remainder
        acc0 += __half2float(hw[csr[e] * 64 + lane]);
    float v = fmaxf(b1[lane] + dd * (((acc0 + acc1) + (acc2 + acc3)) + hself), 0.0f);
    h2out[d * 64 + lane] = __float2half_rn(v);
}

// ---------------- hw2' = dinv * (h2 @ W2)  (64 -> 32), fp16 in/out ---------
__global__ __launch_bounds__(256) void k_hw2(const __half* __restrict__ h2,
                                             const float* __restrict__ W2,
                                             const float* __restrict__ dinv,
                                             __half* __restrict__ hw2) {
    __shared__ float sh[TM2 * 65];  // [node][feat], stride 65 (pad)
    __shared__ float sw[64 * 32];
    int tid = threadIdx.x;
    for (int t = tid; t < 64 * 32; t += 256) sw[t] = W2[t];
    int nb = blockIdx.x * TM2;
    for (int i = tid; i < TM2 * 64; i += 256) {
        int node = i >> 6, ch = i & 63;
        int g = nb + node;
        sh[node * 65 + ch] = (g < NN) ? __half2float(h2[g * 64 + ch]) : 0.0f;
    }
    __syncthreads();
    int j  = (tid & 7) * 4;
    int nl = (tid >> 3) * 4;
    float a00=0,a01=0,a02=0,a03=0, a10=0,a11=0,a12=0,a13=0;
    float a20=0,a21=0,a22=0,a23=0, a30=0,a31=0,a32=0,a33=0;
#pragma unroll 4
    for (int k = 0; k < 64; ++k) {
        float4 wv = *(const float4*)&sw[k * 32 + j];
        float h0 = sh[(nl + 0) * 65 + k];
        float h1 = sh[(nl + 1) * 65 + k];
        float h2v = sh[(nl + 2) * 65 + k];
        float h3 = sh[(nl + 3) * 65 + k];
        a00 += h0 * wv.x;  a01 += h0 * wv.y;  a02 += h0 * wv.z;  a03 += h0 * wv.w;
        a10 += h1 * wv.x;  a11 += h1 * wv.y;  a12 += h1 * wv.z;  a13 += h1 * wv.w;
        a20 += h2v * wv.x; a21 += h2v * wv.y; a22 += h2v * wv.z; a23 += h2v * wv.w;
        a30 += h3 * wv.x;  a31 += h3 * wv.y;  a32 += h3 * wv.z;  a33 += h3 * wv.w;
    }
    int g0 = nb + nl;
    union { __half2 h2v2[2]; float2 f2; } u;
#define STORE_ROW(r, b0, b1, b2, b3)                                          \
    if (g0 + r < NN) {                                                        \
        float sc = dinv[g0 + r];                                              \
        u.h2v2[0] = __floats2half2_rn(b0 * sc, b1 * sc);                      \
        u.h2v2[1] = __floats2half2_rn(b2 * sc, b3 * sc);                      \
        *(float2*)&hw2[(g0 + r) * 32 + j] = u.f2;                            \
    }
    STORE_ROW(0, a00, a01, a02, a03)
    STORE_ROW(1, a10, a11, a12, a13)
    STORE_ROW(2, a20, a21, a22, a23)
    STORE_ROW(3, a30, a31, a32, a33)
#undef STORE_ROW
}

// ---------------- layer-2 gather (R12 loop + linkpred-dot epilogue) --------
// z[d][j] = b2[j] + dinv[d] * (sum_e hw2'[s] + hw2'[d])
// Epilogue also emits u[d] = z[d]·Wl[0:32], v[d] = z[d]·Wl[32:64] so the
// linkpred head becomes two 4B lookups/edge instead of two 128B row gathers.
// z is computed on ALL lanes (acc identical across half pair after the
// xor-32 combine) so the 5-level shuffle dot runs with full exec.
__global__ __launch_bounds__(256) void k_gather2(const int* __restrict__ off,
                                                 const int* __restrict__ csr,
                                                 const float* __restrict__ dinv,
                                                 const __half* __restrict__ hw,
                                                 const float* __restrict__ b2,
                                                 const float* __restrict__ Wl,
                                                 float* __restrict__ outz,
                                                 float* __restrict__ uu,
                                                 float* __restrict__ vv) {
    int lane = threadIdx.x & 63;
    int half = lane >> 5;
    int j = lane & 31;
    int wave = threadIdx.x >> 6;
    int d = blockIdx.x * 4 + wave;             // grid = NN/4 exactly
    int start = (d == 0) ? 0 : off[d - 1];
    int end = off[d];
    start = __builtin_amdgcn_readfirstlane(start);
    end   = __builtin_amdgcn_readfirstlane(end);
    float dd = dinv[d];
    float hself = __half2float(hw[d * 32 + j]);      // hoisted
    float accA = 0.0f, accB = 0.0f, accC = 0.0f, accD = 0.0f;
    int e = start;
    for (; e + 7 < end; e += 8) {              // 4 gathers per half in flight
        int sA = csr[e + half];
        int sB = csr[e + half + 2];
        int sC = csr[e + half + 4];
        int sD = csr[e + half + 6];
        accA += __half2float(hw[sA * 32 + j]);
        accB += __half2float(hw[sB * 32 + j]);
        accC += __half2float(hw[sC * 32 + j]);
        accD += __half2float(hw[sD * 32 + j]);
    }
    for (int ee = e + half; ee < end; ee += 2)       // divergent-safe tail
        accA += __half2float(hw[csr[ee] * 32 + j]);
    float acc = (accA + accB) + (accC + accD);
    acc += __shfl(acc, lane ^ 32, 64);         // combine halves (full exec)
    float z = b2[j] + dd * (acc + hself);      // valid on all lanes
    if (half == 0)
        outz[d * 32 + j] = z;
    // per-node link-pred dots (all lanes; halves compute identical values)
    float p0 = z * Wl[j];
    float p1 = z * Wl[32 + j];
    p0 += __shfl_xor(p0, 1, 64);  p1 += __shfl_xor(p1, 1, 64);
    p0 += __shfl_xor(p0, 2, 64);  p1 += __shfl_xor(p1, 2, 64);
    p0 += __shfl_xor(p0, 4, 64);  p1 += __shfl_xor(p1, 4, 64);
    p0 += __shfl_xor(p0, 8, 64);  p1 += __shfl_xor(p1, 8, 64);
    p0 += __shfl_xor(p0, 16, 64); p1 += __shfl_xor(p1, 16, 64);
    if (lane == 0) { uu[d] = p0; vv[d] = p1; }
}

// ---------------- link prediction head: pred = u[s] + v[d] + bl ------------
// u,v precomputed in k_gather2 (800 KB, L2-resident) — replaces 2x128B
// random z-row gathers per edge (~51 MB fetch) with 2x4B lookups.
__global__ __launch_bounds__(256) void k_linkpred(const int* __restrict__ sidx,
                                                  const int* __restrict__ didx,
                                                  const float* __restrict__ uu,
                                                  const float* __restrict__ vv,
                                                  const float* __restrict__ bl,
                                                  float* __restrict__ pred) {
    int e = blockIdx.x * 256 + threadIdx.x;
    if (e < NEL)
        pred[e] = uu[sidx[e]] + vv[didx[e]] + bl[0];
}

extern "C" void kernel_launch(void* const* d_in, const int* in_sizes, int n_in,
                              void* d_out, int out_size, void* d_ws, size_t ws_size,
                              hipStream_t stream) {
    const float* x    = (const float*)d_in[0];
    const float* pos  = (const float*)d_in[1];
    const float* W1   = (const float*)d_in[2];
    const float* b1   = (const float*)d_in[3];
    const float* W2   = (const float*)d_in[4];
    const float* b2   = (const float*)d_in[5];
    const float* Wl   = (const float*)d_in[6];
    const float* bl   = (const float*)d_in[7];
    const int*   ei   = (const int*)d_in[8];   // [2, NE]
    const int*   eli  = (const int*)d_in[9];   // [2, NEL]
    const int* src  = ei;
    const int* dst  = ei + NE;
    const int* lsrc = eli;
    const int* ldst = eli + NEL;

    float* out_z    = (float*)d_out;            // [NN, 32]
    float* out_pred = (float*)d_out + NN * 32;  // [NEL]

    // workspace: dinv[NN]f | off[NN]i | gcur[NBUCK] | csr[NE]i |
    //            hw1'[NN*64]h (aliases part[NBUCK*CAPB]i = 8.0 MB, dead after
    //            k_build) | h2[NN*64]h (dead after k_hw2 -> reused for uu/vv)
    //            | hw2'[NN*32]h   ~= 39.2 MB
    float*  dinv  = (float*)d_ws;
    int*    off   = (int*)(dinv + NN);
    int*    gcur  = off + NN;
    int*    csr   = gcur + NBUCK;
    __half* hw1   = (__half*)(csr + NE);
    int*    part  = (int*)hw1;                  // 8.0 MB <= hw1's 12.8 MB
    __half* h2    = hw1 + NN * 64;
    __half* hw2   = h2 + NN * 64;
    float*  uu    = (float*)h2;                 // h2 dead after k_hw2
    float*  vv    = uu + NN;

    // 1) CSR build: partition -> per-bucket LDS sort (prefix fused, +dinv)
    hipMemsetAsync(gcur, 0, NBUCK * sizeof(int), stream);
    k_part<<<(NE + TPE - 1) / TPE, 256, 0, stream>>>(src, dst, gcur, part);
    k_build<<<NBUCK, 256, 0, stream>>>(gcur, part, csr, off, dinv);

    // 2) hw1' = dinv * ([x|pos] @ W1), fp16  (overwrites part — now dead)
    k_hw1<<<(NN + TM - 1) / TM, 256, 0, stream>>>(x, pos, W1, dinv, hw1);

    // 3) layer-1 gather + bias + relu -> h2 (fp16), full-wave rows
    k_gather1<<<NN / 4, 256, 0, stream>>>(off, csr, dinv, hw1, b1, h2);

    // 4) hw2' = dinv * (h2 @ W2), fp16
    k_hw2<<<(NN + TM2 - 1) / TM2, 256, 0, stream>>>(h2, W2, dinv, hw2);

    // 5) layer-2 gather + bias -> z (fp32 out) + per-node linkpred dots u,v
    k_gather2<<<NN / 4, 256, 0, stream>>>(off, csr, dinv, hw2, b2, Wl,
                                          out_z, uu, vv);

    // 6) link prediction: pred[e] = u[s] + v[d] + bl
    k_linkpred<<<(NEL + 255) / 256, 256, 0, stream>>>(lsrc, ldst, uu, vv, bl,
                                                      out_pred);
}

// Round 3
// 296.874 us; speedup vs baseline: 2.1189x; 1.0322x over previous
//
#include <hip/hip_runtime.h>
#include <hip/hip_fp16.h>

#define NN 100000     // num nodes
#define NE 1600000    // num edges
#define NEL 200000    // link-pred edges
#define TM 64         // nodes per block in k_hw1
#define TM2 128       // nodes per block in k_hw2

// Bucketed CSR build (R12 config — best measured): bucket = dst >> 9.
#define NBUCK 196     // ceil(NN/512)
#define CAPB  10240   // per-bucket capacity (mean 8163, sigma ~90)
#define TPE   8192    // edges per k_part block (196 blocks)

// ---------------- CSR build, pass A: partition edges into buckets ----------
__global__ __launch_bounds__(256) void k_part(const int* __restrict__ src,
                                              const int* __restrict__ dst,
                                              int* __restrict__ gcur,
                                              int* __restrict__ part) {
    __shared__ int hist[NBUCK];
    __shared__ int base[NBUCK];
    __shared__ int rk[NBUCK];
    int tid = threadIdx.x;
    for (int i = tid; i < NBUCK; i += 256) { hist[i] = 0; rk[i] = 0; }
    __syncthreads();
    int e0 = blockIdx.x * TPE;
    int e1 = min(e0 + TPE, NE);
    for (int e = e0 + tid; e < e1; e += 256)
        atomicAdd(&hist[dst[e] >> 9], 1);
    __syncthreads();
    for (int i = tid; i < NBUCK; i += 256)
        base[i] = i * CAPB + atomicAdd(&gcur[i], hist[i]);
    __syncthreads();
    for (int e = e0 + tid; e < e1; e += 256) {
        int d = dst[e];
        int s = src[e];
        int b = d >> 9;
        int r = atomicAdd(&rk[b], 1);
        part[base[b] + r] = ((d & 511) << 17) | s;   // src < 2^17
    }
}

// ---------------- CSR build, pass B: per-bucket LDS sort (prefix fused) ----
__global__ __launch_bounds__(256) void k_build(const int* __restrict__ gcur,
                                               const int* __restrict__ part,
                                               int* __restrict__ csr,
                                               int* __restrict__ off,
                                               float* __restrict__ dinv) {
    __shared__ int cnts[256];
    __shared__ int hist[512];
    __shared__ int loff[512];
    __shared__ int ssum[256];
    __shared__ int csrbuf[CAPB];
    int b = blockIdx.x;
    int tid = threadIdx.x;
    cnts[tid] = (tid < NBUCK) ? gcur[tid] : 0;       // inline bucket prefix
    __syncthreads();
    for (int st = 1; st < 256; st <<= 1) {
        int tmp = (tid >= st) ? cnts[tid - st] : 0;
        __syncthreads();
        cnts[tid] += tmp;
        __syncthreads();
    }
    int obase = (b == 0) ? 0 : cnts[b - 1];
    int cnt = gcur[b];
    int pbase = b * CAPB;
    hist[tid] = 0; hist[tid + 256] = 0;
    __syncthreads();
    for (int i = tid; i < cnt; i += 256)
        atomicAdd(&hist[part[pbase + i] >> 17], 1);
    __syncthreads();
    int a0 = hist[2 * tid], a1 = hist[2 * tid + 1];
    int pairs = a0 + a1;
    ssum[tid] = pairs;
    __syncthreads();
    for (int st = 1; st < 256; st <<= 1) {
        int tmp = (tid >= st) ? ssum[tid - st] : 0;
        __syncthreads();
        ssum[tid] += tmp;
        __syncthreads();
    }
    int pexcl = ssum[tid] - pairs;
    loff[2 * tid] = pexcl;
    loff[2 * tid + 1] = pexcl + a0;
    __syncthreads();
    for (int i = tid; i < 512; i += 256) {
        int d = b * 512 + i;
        if (d < NN) {
            int c = hist[i];
            off[d] = obase + loff[i] + c;            // end of row d
            dinv[d] = rsqrtf((float)(c + 1));        // +1 self-loop
        }
    }
    hist[tid] = 0; hist[tid + 256] = 0;              // reuse as rank counters
    __syncthreads();
    for (int i = tid; i < cnt; i += 256) {
        int rec = part[pbase + i];
        int dl = rec >> 17;
        int r = atomicAdd(&hist[dl], 1);
        csrbuf[loff[dl] + r] = rec & 0x1FFFF;
    }
    __syncthreads();
    for (int i = tid; i < cnt; i += 256)             // coalesced flush
        csr[obase + i] = csrbuf[i];
}

// ---------------- hw1' = dinv * ([x|pos] @ W1)  (80 -> 64), fp16 out -------
__global__ __launch_bounds__(256) void k_hw1(const float* __restrict__ x,
                                             const float* __restrict__ pos,
                                             const float* __restrict__ W1,
                                             const float* __restrict__ dinv,
                                             __half* __restrict__ hw1) {
    __shared__ float sh[TM * 80];
    __shared__ float sw[80 * 64];
    int tid = threadIdx.x;
    for (int t = tid; t < 80 * 64; t += 256) sw[t] = W1[t];
    int nb = blockIdx.x * TM;
    for (int i = tid; i < TM * 64; i += 256) {
        int node = i >> 6, ch = i & 63;
        int g = nb + node;
        sh[node * 80 + ch] = (g < NN) ? x[g * 64 + ch] : 0.0f;
    }
    for (int i = tid; i < TM * 16; i += 256) {
        int node = i >> 4, ch = i & 15;
        int g = nb + node;
        sh[node * 80 + 64 + ch] = (g < NN) ? pos[g * 16 + ch] : 0.0f;
    }
    __syncthreads();
    int j  = (tid & 15) * 4;
    int nl = (tid >> 4) * 4;
    float a00=0,a01=0,a02=0,a03=0, a10=0,a11=0,a12=0,a13=0;
    float a20=0,a21=0,a22=0,a23=0, a30=0,a31=0,a32=0,a33=0;
#pragma unroll 4
    for (int k = 0; k < 80; ++k) {
        float4 wv = *(const float4*)&sw[k * 64 + j];
        float h0 = sh[(nl + 0) * 80 + k];
        float h1 = sh[(nl + 1) * 80 + k];
        float h2 = sh[(nl + 2) * 80 + k];
        float h3 = sh[(nl + 3) * 80 + k];
        a00 += h0 * wv.x; a01 += h0 * wv.y; a02 += h0 * wv.z; a03 += h0 * wv.w;
        a10 += h1 * wv.x; a11 += h1 * wv.y; a12 += h1 * wv.z; a13 += h1 * wv.w;
        a20 += h2 * wv.x; a21 += h2 * wv.y; a22 += h2 * wv.z; a23 += h2 * wv.w;
        a30 += h3 * wv.x; a31 += h3 * wv.y; a32 += h3 * wv.z; a33 += h3 * wv.w;
    }
    int g0 = nb + nl;
    union { __half2 h2v[2]; float2 f2; } u;
#define STORE_ROW(r, b0, b1, b2, b3)                                          \
    if (g0 + r < NN) {                                                        \
        float sc = dinv[g0 + r];                                              \
        u.h2v[0] = __floats2half2_rn(b0 * sc, b1 * sc);                       \
        u.h2v[1] = __floats2half2_rn(b2 * sc, b3 * sc);                       \
        *(float2*)&hw1[(g0 + r) * 64 + j] = u.f2;                             \
    }
    STORE_ROW(0, a00, a01, a02, a03)
    STORE_ROW(1, a10, a11, a12, a13)
    STORE_ROW(2, a20, a21, a22, a23)
    STORE_ROW(3, a30, a31, a32, a33)
#undef STORE_ROW
}

// ---------------- layer-1 gather (R18: masked 16-deep, tail-free) ----------
// h2[d][c] = relu(b1[c] + dinv[d] * (sum_e hw1'[s] + hw1'[d]))
// One masked batch loop: out-of-range slots clamp to csr[e] (slot 0, always
// valid) so the extra request coalesces with slot 0's line; the duplicate
// g0 contributions are removed arithmetically (acc -= inv*g0). No per-slot
// mask registers, no serial remainder loop (the old tail was ~3.5 serial
// full-latency loads per row — likely the dominant per-row cost).
// R15 channel-slicing regressed 3.2x — do not re-slice.
// R16 index arrays regressed 5x (scratch spill) — named scalars only.
__global__ __launch_bounds__(256) void k_gather1(const int* __restrict__ off,
                                                 const int* __restrict__ csr,
                                                 const float* __restrict__ dinv,
                                                 const __half* __restrict__ hw,
                                                 const float* __restrict__ b1,
                                                 __half* __restrict__ h2out) {
    int lane = threadIdx.x & 63;
    int wave = threadIdx.x >> 6;
    int d = blockIdx.x * 4 + wave;             // grid = NN/4 exactly
    int start = (d == 0) ? 0 : off[d - 1];
    int end = off[d];
    start = __builtin_amdgcn_readfirstlane(start);   // SGPR bounds ->
    end   = __builtin_amdgcn_readfirstlane(end);     // scalar csr loads
    float dd = dinv[d];
    float hself = __half2float(hw[d * 64 + lane]);   // hoisted
    float acc0 = 0.0f, acc1 = 0.0f, acc2 = 0.0f, acc3 = 0.0f;
    for (int e = start; e < end; e += 16) {
        int rem = end - e;                     // >= 1 (SGPR)
        int s0 = csr[e];
        int s1  = (rem > 1)  ? csr[e + 1]  : s0;
        int s2  = (rem > 2)  ? csr[e + 2]  : s0;
        int s3  = (rem > 3)  ? csr[e + 3]  : s0;
        int s4  = (rem > 4)  ? csr[e + 4]  : s0;
        int s5  = (rem > 5)  ? csr[e + 5]  : s0;
        int s6  = (rem > 6)  ? csr[e + 6]  : s0;
        int s7  = (rem > 7)  ? csr[e + 7]  : s0;
        int s8  = (rem > 8)  ? csr[e + 8]  : s0;
        int s9  = (rem > 9)  ? csr[e + 9]  : s0;
        int s10 = (rem > 10) ? csr[e + 10] : s0;
        int s11 = (rem > 11) ? csr[e + 11] : s0;
        int s12 = (rem > 12) ? csr[e + 12] : s0;
        int s13 = (rem > 13) ? csr[e + 13] : s0;
        int s14 = (rem > 14) ? csr[e + 14] : s0;
        int s15 = (rem > 15) ? csr[e + 15] : s0;
        float g0  = __half2float(hw[s0  * 64 + lane]);
        float g1  = __half2float(hw[s1  * 64 + lane]);
        float g2  = __half2float(hw[s2  * 64 + lane]);
        float g3  = __half2float(hw[s3  * 64 + lane]);
        float g4  = __half2float(hw[s4  * 64 + lane]);
        float g5  = __half2float(hw[s5  * 64 + lane]);
        float g6  = __half2float(hw[s6  * 64 + lane]);
        float g7  = __half2float(hw[s7  * 64 + lane]);
        float g8  = __half2float(hw[s8  * 64 + lane]);
        float g9  = __half2float(hw[s9  * 64 + lane]);
        float g10 = __half2float(hw[s10 * 64 + lane]);
        float g11 = __half2float(hw[s11 * 64 + lane]);
        float g12 = __half2float(hw[s12 * 64 + lane]);
        float g13 = __half2float(hw[s13 * 64 + lane]);
        float g14 = __half2float(hw[s14 * 64 + lane]);
        float g15 = __half2float(hw[s15 * 64 + lane]);
        int inv = 16 - rem;
        if (inv < 0) inv = 0;                  // # clamped slots (SGPR)
        acc0 += g0;  acc1 += g1;  acc2 += g2;  acc3 += g3;
        acc0 += g4;  acc1 += g5;  acc2 += g6;  acc3 += g7;
        acc0 += g8;  acc1 += g9;  acc2 += g10; acc3 += g11;
        acc0 += g12; acc1 += g13; acc2 += g14; acc3 += g15;
        acc3 = fmaf(-(float)inv, g0, acc3);    // remove clamped duplicates
    }
    float v = fmaxf(b1[lane] + dd * (((acc0 + acc1) + (acc2 + acc3)) + hself), 0.0f);
    h2out[d * 64 + lane] = __float2half_rn(v);
}

// ---------------- hw2' = dinv * (h2 @ W2)  (64 -> 32), fp16 in/out ---------
__global__ __launch_bounds__(256) void k_hw2(const __half* __restrict__ h2,
                                             const float* __restrict__ W2,
                                             const float* __restrict__ dinv,
                                             __half* __restrict__ hw2) {
    __shared__ float sh[TM2 * 65];  // [node][feat], stride 65 (pad)
    __shared__ float sw[64 * 32];
    int tid = threadIdx.x;
    for (int t = tid; t < 64 * 32; t += 256) sw[t] = W2[t];
    int nb = blockIdx.x * TM2;
    for (int i = tid; i < TM2 * 64; i += 256) {
        int node = i >> 6, ch = i & 63;
        int g = nb + node;
        sh[node * 65 + ch] = (g < NN) ? __half2float(h2[g * 64 + ch]) : 0.0f;
    }
    __syncthreads();
    int j  = (tid & 7) * 4;
    int nl = (tid >> 3) * 4;
    float a00=0,a01=0,a02=0,a03=0, a10=0,a11=0,a12=0,a13=0;
    float a20=0,a21=0,a22=0,a23=0, a30=0,a31=0,a32=0,a33=0;
#pragma unroll 4
    for (int k = 0; k < 64; ++k) {
        float4 wv = *(const float4*)&sw[k * 32 + j];
        float h0 = sh[(nl + 0) * 65 + k];
        float h1 = sh[(nl + 1) * 65 + k];
        float h2v = sh[(nl + 2) * 65 + k];
        float h3 = sh[(nl + 3) * 65 + k];
        a00 += h0 * wv.x;  a01 += h0 * wv.y;  a02 += h0 * wv.z;  a03 += h0 * wv.w;
        a10 += h1 * wv.x;  a11 += h1 * wv.y;  a12 += h1 * wv.z;  a13 += h1 * wv.w;
        a20 += h2v * wv.x; a21 += h2v * wv.y; a22 += h2v * wv.z; a23 += h2v * wv.w;
        a30 += h3 * wv.x;  a31 += h3 * wv.y;  a32 += h3 * wv.z;  a33 += h3 * wv.w;
    }
    int g0 = nb + nl;
    union { __half2 h2v2[2]; float2 f2; } u;
#define STORE_ROW(r, b0, b1, b2, b3)                                          \
    if (g0 + r < NN) {                                                        \
        float sc = dinv[g0 + r];                                              \
        u.h2v2[0] = __floats2half2_rn(b0 * sc, b1 * sc);                      \
        u.h2v2[1] = __floats2half2_rn(b2 * sc, b3 * sc);                      \
        *(float2*)&hw2[(g0 + r) * 32 + j] = u.f2;                            \
    }
    STORE_ROW(0, a00, a01, a02, a03)
    STORE_ROW(1, a10, a11, a12, a13)
    STORE_ROW(2, a20, a21, a22, a23)
    STORE_ROW(3, a30, a31, a32, a33)
#undef STORE_ROW
}

// ---------------- layer-2 gather (R18: masked 16-deep, tail-free) ----------
// z[d][j] = b2[j] + dinv[d] * (sum_e hw2'[s] + hw2'[d])
// 16 edges/iter (8 per half in flight). Out-of-range slots clamp to csr[e]
// (its line coalesces with the half-0 lanes' slot in the same instruction).
// Validity is monotone in slot index, so whenever inv>0 the LAST slot (gH)
// holds the clamped value r0 — correction: acc -= inv*gH.
// Epilogue emits u[d] = z·Wl[0:32], v[d] = z·Wl[32:64] for the linkpred head.
__global__ __launch_bounds__(256) void k_gather2(const int* __restrict__ off,
                                                 const int* __restrict__ csr,
                                                 const float* __restrict__ dinv,
                                                 const __half* __restrict__ hw,
                                                 const float* __restrict__ b2,
                                                 const float* __restrict__ Wl,
                                                 float* __restrict__ outz,
                                                 float* __restrict__ uu,
                                                 float* __restrict__ vv) {
    int lane = threadIdx.x & 63;
    int half = lane >> 5;
    int j = lane & 31;
    int wave = threadIdx.x >> 6;
    int d = blockIdx.x * 4 + wave;             // grid = NN/4 exactly
    int start = (d == 0) ? 0 : off[d - 1];
    int end = off[d];
    start = __builtin_amdgcn_readfirstlane(start);
    end   = __builtin_amdgcn_readfirstlane(end);
    float dd = dinv[d];
    float hself = __half2float(hw[d * 32 + j]);      // hoisted
    float accA = 0.0f, accB = 0.0f, accC = 0.0f, accD = 0.0f;
    for (int e = start; e < end; e += 16) {
        int rem = end - e;                     // >= 1 (SGPR)
        int s0 = csr[e];                       // clamp target (uniform)
        int i1 = e + half;
        int sA = (half      < rem) ? csr[i1]      : s0;
        int sB = (half + 2  < rem) ? csr[i1 + 2]  : s0;
        int sC = (half + 4  < rem) ? csr[i1 + 4]  : s0;
        int sD = (half + 6  < rem) ? csr[i1 + 6]  : s0;
        int sE = (half + 8  < rem) ? csr[i1 + 8]  : s0;
        int sF = (half + 10 < rem) ? csr[i1 + 10] : s0;
        int sG = (half + 12 < rem) ? csr[i1 + 12] : s0;
        int sH = (half + 14 < rem) ? csr[i1 + 14] : s0;
        float gA = __half2float(hw[sA * 32 + j]);
        float gB = __half2float(hw[sB * 32 + j]);
        float gC = __half2float(hw[sC * 32 + j]);
        float gD = __half2float(hw[sD * 32 + j]);
        float gE = __half2float(hw[sE * 32 + j]);
        float gF = __half2float(hw[sF * 32 + j]);
        float gG = __half2float(hw[sG * 32 + j]);
        float gH = __half2float(hw[sH * 32 + j]);
        int nv = (rem - half + 1) >> 1;        // valid slots this half
        if (nv > 8) nv = 8;
        int inv = 8 - nv;                      // clamped slots this half
        accA += gA; accB += gB; accC += gC; accD += gD;
        accA += gE; accB += gF; accC += gG; accD += gH;
        accD = fmaf(-(float)inv, gH, accD);    // gH == r0 whenever inv > 0
    }
    float acc = (accA + accB) + (accC + accD);
    acc += __shfl(acc, lane ^ 32, 64);         // combine halves (full exec)
    float z = b2[j] + dd * (acc + hself);      // valid on all lanes
    if (half == 0)
        outz[d * 32 + j] = z;
    // per-node link-pred dots (all lanes; halves compute identical values)
    float p0 = z * Wl[j];
    float p1 = z * Wl[32 + j];
    p0 += __shfl_xor(p0, 1, 64);  p1 += __shfl_xor(p1, 1, 64);
    p0 += __shfl_xor(p0, 2, 64);  p1 += __shfl_xor(p1, 2, 64);
    p0 += __shfl_xor(p0, 4, 64);  p1 += __shfl_xor(p1, 4, 64);
    p0 += __shfl_xor(p0, 8, 64);  p1 += __shfl_xor(p1, 8, 64);
    p0 += __shfl_xor(p0, 16, 64); p1 += __shfl_xor(p1, 16, 64);
    if (lane == 0) { uu[d] = p0; vv[d] = p1; }
}

// ---------------- link prediction head: pred = u[s] + v[d] + bl ------------
__global__ __launch_bounds__(256) void k_linkpred(const int* __restrict__ sidx,
                                                  const int* __restrict__ didx,
                                                  const float* __restrict__ uu,
                                                  const float* __restrict__ vv,
                                                  const float* __restrict__ bl,
                                                  float* __restrict__ pred) {
    int e = blockIdx.x * 256 + threadIdx.x;
    if (e < NEL)
        pred[e] = uu[sidx[e]] + vv[didx[e]] + bl[0];
}

extern "C" void kernel_launch(void* const* d_in, const int* in_sizes, int n_in,
                              void* d_out, int out_size, void* d_ws, size_t ws_size,
                              hipStream_t stream) {
    const float* x    = (const float*)d_in[0];
    const float* pos  = (const float*)d_in[1];
    const float* W1   = (const float*)d_in[2];
    const float* b1   = (const float*)d_in[3];
    const float* W2   = (const float*)d_in[4];
    const float* b2   = (const float*)d_in[5];
    const float* Wl   = (const float*)d_in[6];
    const float* bl   = (const float*)d_in[7];
    const int*   ei   = (const int*)d_in[8];   // [2, NE]
    const int*   eli  = (const int*)d_in[9];   // [2, NEL]
    const int* src  = ei;
    const int* dst  = ei + NE;
    const int* lsrc = eli;
    const int* ldst = eli + NEL;

    float* out_z    = (float*)d_out;            // [NN, 32]
    float* out_pred = (float*)d_out + NN * 32;  // [NEL]

    // workspace: dinv[NN]f | off[NN]i | gcur[NBUCK] | csr[NE]i |
    //            hw1'[NN*64]h (aliases part[NBUCK*CAPB]i = 8.0 MB, dead after
    //            k_build; also provides safe slack for the <=15-int csr
    //            over-reads in the masked gather loops) | h2[NN*64]h (dead
    //            after k_hw2 -> reused for uu/vv) | hw2'[NN*32]h  ~= 39.2 MB
    float*  dinv  = (float*)d_ws;
    int*    off   = (int*)(dinv + NN);
    int*    gcur  = off + NN;
    int*    csr   = gcur + NBUCK;
    __half* hw1   = (__half*)(csr + NE);
    int*    part  = (int*)hw1;                  // 8.0 MB <= hw1's 12.8 MB
    __half* h2    = hw1 + NN * 64;
    __half* hw2   = h2 + NN * 64;
    float*  uu    = (float*)h2;                 // h2 dead after k_hw2
    float*  vv    = uu + NN;

    // 1) CSR build: partition -> per-bucket LDS sort (prefix fused, +dinv)
    hipMemsetAsync(gcur, 0, NBUCK * sizeof(int), stream);
    k_part<<<(NE + TPE - 1) / TPE, 256, 0, stream>>>(src, dst, gcur, part);
    k_build<<<NBUCK, 256, 0, stream>>>(gcur, part, csr, off, dinv);

    // 2) hw1' = dinv * ([x|pos] @ W1), fp16  (overwrites part — now dead)
    k_hw1<<<(NN + TM - 1) / TM, 256, 0, stream>>>(x, pos, W1, dinv, hw1);

    // 3) layer-1 gather + bias + relu -> h2 (fp16), masked 16-deep
    k_gather1<<<NN / 4, 256, 0, stream>>>(off, csr, dinv, hw1, b1, h2);

    // 4) hw2' = dinv * (h2 @ W2), fp16
    k_hw2<<<(NN + TM2 - 1) / TM2, 256, 0, stream>>>(h2, W2, dinv, hw2);

    // 5) layer-2 gather + bias -> z (fp32 out) + per-node linkpred dots u,v
    k_gather2<<<NN / 4, 256, 0, stream>>>(off, csr, dinv, hw2, b2, Wl,
                                          out_z, uu, vv);

    // 6) link prediction: pred[e] = u[s] + v[d] + bl
    k_linkpred<<<(NEL + 255) / 256, 256, 0, stream>>>(lsrc, ldst, uu, vv, bl,
                                                      out_pred);
}

// Round 4
// 290.144 us; speedup vs baseline: 2.1681x; 1.0232x over previous
//
#include <hip/hip_runtime.h>
#include <hip/hip_fp16.h>

#define NN 100000     // num nodes
#define NE 1600000    // num edges
#define NEL 200000    // link-pred edges

// Bucketed CSR build (R12 config — best measured): bucket = dst >> 9.
#define NBUCK 196     // ceil(NN/512)
#define CAPB  10240   // per-bucket capacity (mean 8163, sigma ~90)
#define TPE   8192    // edges per k_part block (196 blocks)

typedef short s16x8 __attribute__((ext_vector_type(8)));
typedef float f32x4 __attribute__((ext_vector_type(4)));

__device__ __forceinline__ unsigned short bf16hi(float v) {
    unsigned u = __float_as_uint(v);
    return (unsigned short)((u + 0x7FFFu + ((u >> 16) & 1u)) >> 16);
}
__device__ __forceinline__ float bf16tof(unsigned short b) {
    return __uint_as_float(((unsigned)b) << 16);
}

// ---------------- CSR build, pass A: partition edges into buckets ----------
__global__ __launch_bounds__(256) void k_part(const int* __restrict__ src,
                                              const int* __restrict__ dst,
                                              int* __restrict__ gcur,
                                              int* __restrict__ part) {
    __shared__ int hist[NBUCK];
    __shared__ int base[NBUCK];
    __shared__ int rk[NBUCK];
    int tid = threadIdx.x;
    for (int i = tid; i < NBUCK; i += 256) { hist[i] = 0; rk[i] = 0; }
    __syncthreads();
    int e0 = blockIdx.x * TPE;
    int e1 = min(e0 + TPE, NE);
    for (int e = e0 + tid; e < e1; e += 256)
        atomicAdd(&hist[dst[e] >> 9], 1);
    __syncthreads();
    for (int i = tid; i < NBUCK; i += 256)
        base[i] = i * CAPB + atomicAdd(&gcur[i], hist[i]);
    __syncthreads();
    for (int e = e0 + tid; e < e1; e += 256) {
        int d = dst[e];
        int s = src[e];
        int b = d >> 9;
        int r = atomicAdd(&rk[b], 1);
        part[base[b] + r] = ((d & 511) << 17) | s;   // src < 2^17
    }
}

// ---------------- CSR build, pass B: per-bucket LDS sort (prefix fused) ----
__global__ __launch_bounds__(256) void k_build(const int* __restrict__ gcur,
                                               const int* __restrict__ part,
                                               int* __restrict__ csr,
                                               int* __restrict__ off,
                                               float* __restrict__ dinv) {
    __shared__ int cnts[256];
    __shared__ int hist[512];
    __shared__ int loff[512];
    __shared__ int ssum[256];
    __shared__ int csrbuf[CAPB];
    int b = blockIdx.x;
    int tid = threadIdx.x;
    cnts[tid] = (tid < NBUCK) ? gcur[tid] : 0;       // inline bucket prefix
    __syncthreads();
    for (int st = 1; st < 256; st <<= 1) {
        int tmp = (tid >= st) ? cnts[tid - st] : 0;
        __syncthreads();
        cnts[tid] += tmp;
        __syncthreads();
    }
    int obase = (b == 0) ? 0 : cnts[b - 1];
    int cnt = gcur[b];
    int pbase = b * CAPB;
    hist[tid] = 0; hist[tid + 256] = 0;
    __syncthreads();
    for (int i = tid; i < cnt; i += 256)
        atomicAdd(&hist[part[pbase + i] >> 17], 1);
    __syncthreads();
    int a0 = hist[2 * tid], a1 = hist[2 * tid + 1];
    int pairs = a0 + a1;
    ssum[tid] = pairs;
    __syncthreads();
    for (int st = 1; st < 256; st <<= 1) {
        int tmp = (tid >= st) ? ssum[tid - st] : 0;
        __syncthreads();
        ssum[tid] += tmp;
        __syncthreads();
    }
    int pexcl = ssum[tid] - pairs;
    loff[2 * tid] = pexcl;
    loff[2 * tid + 1] = pexcl + a0;
    __syncthreads();
    for (int i = tid; i < 512; i += 256) {
        int d = b * 512 + i;
        if (d < NN) {
            int c = hist[i];
            off[d] = obase + loff[i] + c;            // end of row d
            dinv[d] = rsqrtf((float)(c + 1));        // +1 self-loop
        }
    }
    hist[tid] = 0; hist[tid + 256] = 0;              // reuse as rank counters
    __syncthreads();
    for (int i = tid; i < cnt; i += 256) {
        int rec = part[pbase + i];
        int dl = rec >> 17;
        int r = atomicAdd(&hist[dl], 1);
        csrbuf[loff[dl] + r] = rec & 0x1FFFF;
    }
    __syncthreads();
    for (int i = tid; i < cnt; i += 256)             // coalesced flush
        csr[obase + i] = csrbuf[i];
}

// ---------------- hw1' = dinv * ([x|pos] @ W1)  (80 -> 64), MFMA bf16-split
// R19: bf16 hi/lo split matmul (Ahi*Bhi + Ahi*Blo + Alo*Bhi) on
// mfma_f32_16x16x32_bf16 — fp32-class accuracy, so absmax is unchanged vs
// the old fp32-VALU version. K=80 zero-padded to 96 (3 k-steps), LDS stride
// 104 halves (16B-aligned b128 frags; bank starts 20r%32 = 8 quads x 2-way,
// conflict-free). Old VALU version was LDS-pipe-bound (~5 LDS reads per
// 16 FMA per k); total matmul is only ~1 GFLOP so compute must be ~free.
#define HW1_K 104
__global__ __launch_bounds__(256) void k_hw1(const float* __restrict__ x,
                                             const float* __restrict__ pos,
                                             const float* __restrict__ W1,
                                             const float* __restrict__ dinv,
                                             __half* __restrict__ hw1) {
    __shared__ unsigned short ahi[64 * HW1_K];
    __shared__ unsigned short alo[64 * HW1_K];
    __shared__ unsigned short bhi[64 * HW1_K];
    __shared__ unsigned short blo[64 * HW1_K];
    __shared__ float sdin[64];
    int tid = threadIdx.x;
    int nb = blockIdx.x * 64;
    // zero k-pad (k = 80..103) for both A rows and B cols (64 each)
    for (int i = tid; i < 64 * 24; i += 256) {
        int r = i / 24, c = i - r * 24;
        ahi[r * HW1_K + 80 + c] = 0; alo[r * HW1_K + 80 + c] = 0;
        bhi[r * HW1_K + 80 + c] = 0; blo[r * HW1_K + 80 + c] = 0;
    }
    // stage x -> k 0..63
    for (int i = tid; i < 64 * 64; i += 256) {
        int r = i >> 6, c = i & 63;
        int g = nb + r;
        float v = (g < NN) ? x[g * 64 + c] : 0.0f;
        unsigned short h = bf16hi(v);
        ahi[r * HW1_K + c] = h;
        alo[r * HW1_K + c] = bf16hi(v - bf16tof(h));
    }
    // stage pos -> k 64..79
    for (int i = tid; i < 64 * 16; i += 256) {
        int r = i >> 4, c = i & 15;
        int g = nb + r;
        float v = (g < NN) ? pos[g * 16 + c] : 0.0f;
        unsigned short h = bf16hi(v);
        ahi[r * HW1_K + 64 + c] = h;
        alo[r * HW1_K + 64 + c] = bf16hi(v - bf16tof(h));
    }
    // stage W1 transposed: b[c][k] = W1[k][c]
    for (int i = tid; i < 80 * 64; i += 256) {
        int k = i >> 6, c = i & 63;
        float v = W1[i];
        unsigned short h = bf16hi(v);
        bhi[c * HW1_K + k] = h;
        blo[c * HW1_K + k] = bf16hi(v - bf16tof(h));
    }
    for (int i = tid; i < 64; i += 256) {
        int g = nb + i;
        sdin[i] = (g < NN) ? dinv[g] : 0.0f;
    }
    __syncthreads();
    int wave = tid >> 6, lane = tid & 63;
    int frow = lane & 15, fq = lane >> 4;
    int r0 = wave * 16;                        // wave owns 16 rows x 64 cols
    int aoff = (r0 + frow) * HW1_K + fq * 8;
    s16x8 ah0 = *(s16x8*)&ahi[aoff];
    s16x8 ah1 = *(s16x8*)&ahi[aoff + 32];
    s16x8 ah2 = *(s16x8*)&ahi[aoff + 64];
    s16x8 al0 = *(s16x8*)&alo[aoff];
    s16x8 al1 = *(s16x8*)&alo[aoff + 32];
    s16x8 al2 = *(s16x8*)&alo[aoff + 64];
    f32x4 acc[4];
#pragma unroll
    for (int ct = 0; ct < 4; ++ct) {
        acc[ct] = (f32x4)(0.0f);
        int boff = (ct * 16 + frow) * HW1_K + fq * 8;
        s16x8 bh0 = *(s16x8*)&bhi[boff];
        s16x8 bh1 = *(s16x8*)&bhi[boff + 32];
        s16x8 bh2 = *(s16x8*)&bhi[boff + 64];
        s16x8 bl0 = *(s16x8*)&blo[boff];
        s16x8 bl1 = *(s16x8*)&blo[boff + 32];
        s16x8 bl2 = *(s16x8*)&blo[boff + 64];
        acc[ct] = __builtin_amdgcn_mfma_f32_16x16x32_bf16(ah0, bh0, acc[ct], 0, 0, 0);
        acc[ct] = __builtin_amdgcn_mfma_f32_16x16x32_bf16(ah1, bh1, acc[ct], 0, 0, 0);
        acc[ct] = __builtin_amdgcn_mfma_f32_16x16x32_bf16(ah2, bh2, acc[ct], 0, 0, 0);
        acc[ct] = __builtin_amdgcn_mfma_f32_16x16x32_bf16(ah0, bl0, acc[ct], 0, 0, 0);
        acc[ct] = __builtin_amdgcn_mfma_f32_16x16x32_bf16(ah1, bl1, acc[ct], 0, 0, 0);
        acc[ct] = __builtin_amdgcn_mfma_f32_16x16x32_bf16(ah2, bl2, acc[ct], 0, 0, 0);
        acc[ct] = __builtin_amdgcn_mfma_f32_16x16x32_bf16(al0, bh0, acc[ct], 0, 0, 0);
        acc[ct] = __builtin_amdgcn_mfma_f32_16x16x32_bf16(al1, bh1, acc[ct], 0, 0, 0);
        acc[ct] = __builtin_amdgcn_mfma_f32_16x16x32_bf16(al2, bh2, acc[ct], 0, 0, 0);
    }
#pragma unroll
    for (int ct = 0; ct < 4; ++ct) {
        int col = ct * 16 + frow;
#pragma unroll
        for (int i = 0; i < 4; ++i) {
            int r = r0 + fq * 4 + i;           // C/D: col=lane&15, row=(lane>>4)*4+i
            int g = nb + r;
            if (g < NN)
                hw1[g * 64 + col] = __float2half_rn(acc[ct][i] * sdin[r]);
        }
    }
}

// ---------------- layer-1 gather (R18: masked 16-deep, tail-free) ----------
// At the chip random-line request ceiling (~30 req/ns) — R3 confirmed
// deepening MLP 8->16 gains only 5%; FETCH flat. Do not restructure.
// R15 channel-slicing regressed 3.2x; R16 index arrays regressed 5x (spill).
__global__ __launch_bounds__(256) void k_gather1(const int* __restrict__ off,
                                                 const int* __restrict__ csr,
                                                 const float* __restrict__ dinv,
                                                 const __half* __restrict__ hw,
                                                 const float* __restrict__ b1,
                                                 __half* __restrict__ h2out) {
    int lane = threadIdx.x & 63;
    int wave = threadIdx.x >> 6;
    int d = blockIdx.x * 4 + wave;             // grid = NN/4 exactly
    int start = (d == 0) ? 0 : off[d - 1];
    int end = off[d];
    start = __builtin_amdgcn_readfirstlane(start);   // SGPR bounds ->
    end   = __builtin_amdgcn_readfirstlane(end);     // scalar csr loads
    float dd = dinv[d];
    float hself = __half2float(hw[d * 64 + lane]);   // hoisted
    float acc0 = 0.0f, acc1 = 0.0f, acc2 = 0.0f, acc3 = 0.0f;
    for (int e = start; e < end; e += 16) {
        int rem = end - e;                     // >= 1 (SGPR)
        int s0 = csr[e];
        int s1  = (rem > 1)  ? csr[e + 1]  : s0;
        int s2  = (rem > 2)  ? csr[e + 2]  : s0;
        int s3  = (rem > 3)  ? csr[e + 3]  : s0;
        int s4  = (rem > 4)  ? csr[e + 4]  : s0;
        int s5  = (rem > 5)  ? csr[e + 5]  : s0;
        int s6  = (rem > 6)  ? csr[e + 6]  : s0;
        int s7  = (rem > 7)  ? csr[e + 7]  : s0;
        int s8  = (rem > 8)  ? csr[e + 8]  : s0;
        int s9  = (rem > 9)  ? csr[e + 9]  : s0;
        int s10 = (rem > 10) ? csr[e + 10] : s0;
        int s11 = (rem > 11) ? csr[e + 11] : s0;
        int s12 = (rem > 12) ? csr[e + 12] : s0;
        int s13 = (rem > 13) ? csr[e + 13] : s0;
        int s14 = (rem > 14) ? csr[e + 14] : s0;
        int s15 = (rem > 15) ? csr[e + 15] : s0;
        float g0  = __half2float(hw[s0  * 64 + lane]);
        float g1  = __half2float(hw[s1  * 64 + lane]);
        float g2  = __half2float(hw[s2  * 64 + lane]);
        float g3  = __half2float(hw[s3  * 64 + lane]);
        float g4  = __half2float(hw[s4  * 64 + lane]);
        float g5  = __half2float(hw[s5  * 64 + lane]);
        float g6  = __half2float(hw[s6  * 64 + lane]);
        float g7  = __half2float(hw[s7  * 64 + lane]);
        float g8  = __half2float(hw[s8  * 64 + lane]);
        float g9  = __half2float(hw[s9  * 64 + lane]);
        float g10 = __half2float(hw[s10 * 64 + lane]);
        float g11 = __half2float(hw[s11 * 64 + lane]);
        float g12 = __half2float(hw[s12 * 64 + lane]);
        float g13 = __half2float(hw[s13 * 64 + lane]);
        float g14 = __half2float(hw[s14 * 64 + lane]);
        float g15 = __half2float(hw[s15 * 64 + lane]);
        int inv = 16 - rem;
        if (inv < 0) inv = 0;                  // # clamped slots (SGPR)
        acc0 += g0;  acc1 += g1;  acc2 += g2;  acc3 += g3;
        acc0 += g4;  acc1 += g5;  acc2 += g6;  acc3 += g7;
        acc0 += g8;  acc1 += g9;  acc2 += g10; acc3 += g11;
        acc0 += g12; acc1 += g13; acc2 += g14; acc3 += g15;
        acc3 = fmaf(-(float)inv, g0, acc3);    // remove clamped duplicates
    }
    float v = fmaxf(b1[lane] + dd * (((acc0 + acc1) + (acc2 + acc3)) + hself), 0.0f);
    h2out[d * 64 + lane] = __float2half_rn(v);
}

// ---------------- hw2' = dinv * (h2 @ W2)  (64 -> 32), MFMA bf16-split -----
// h2 fp16 splits into bf16 hi/lo exactly; W2 split likewise -> fp32-class.
// K=64 = 2 k-steps, stride 72 halves (16B-aligned, conflict-free quads).
#define HW2_K 72
__global__ __launch_bounds__(256) void k_hw2(const __half* __restrict__ h2,
                                             const float* __restrict__ W2,
                                             const float* __restrict__ dinv,
                                             __half* __restrict__ hw2) {
    __shared__ unsigned short ahi[128 * HW2_K];
    __shared__ unsigned short alo[128 * HW2_K];
    __shared__ unsigned short bhi[32 * HW2_K];
    __shared__ unsigned short blo[32 * HW2_K];
    __shared__ float sdin[128];
    int tid = threadIdx.x;
    int nb = blockIdx.x * 128;
    // stage h2 (fp16, exact in hi+lo bf16)
    for (int i = tid; i < 128 * 32; i += 256) {
        int r = i >> 5, cp = i & 31;
        int g = nb + r;
        __half2 hv = (g < NN) ? ((const __half2*)h2)[g * 32 + cp]
                              : __floats2half2_rn(0.0f, 0.0f);
        float2 f = __half22float2(hv);
        unsigned short h0 = bf16hi(f.x), h1 = bf16hi(f.y);
        ahi[r * HW2_K + 2 * cp]     = h0;
        ahi[r * HW2_K + 2 * cp + 1] = h1;
        alo[r * HW2_K + 2 * cp]     = bf16hi(f.x - bf16tof(h0));
        alo[r * HW2_K + 2 * cp + 1] = bf16hi(f.y - bf16tof(h1));
    }
    // stage W2 transposed: b[c][k] = W2[k][c]
    for (int i = tid; i < 64 * 32; i += 256) {
        int k = i >> 5, c = i & 31;
        float v = W2[i];
        unsigned short h = bf16hi(v);
        bhi[c * HW2_K + k] = h;
        blo[c * HW2_K + k] = bf16hi(v - bf16tof(h));
    }
    for (int i = tid; i < 128; i += 256) {
        int g = nb + i;
        sdin[i] = (g < NN) ? dinv[g] : 0.0f;
    }
    __syncthreads();
    int wave = tid >> 6, lane = tid & 63;
    int frow = lane & 15, fq = lane >> 4;
    int r0 = wave * 32;                        // wave owns 32 rows x 32 cols
    f32x4 acc[2][2];
#pragma unroll
    for (int rt = 0; rt < 2; ++rt) {
        int aoff = (r0 + rt * 16 + frow) * HW2_K + fq * 8;
        s16x8 ah0 = *(s16x8*)&ahi[aoff];
        s16x8 ah1 = *(s16x8*)&ahi[aoff + 32];
        s16x8 al0 = *(s16x8*)&alo[aoff];
        s16x8 al1 = *(s16x8*)&alo[aoff + 32];
#pragma unroll
        for (int ct = 0; ct < 2; ++ct) {
            acc[rt][ct] = (f32x4)(0.0f);
            int boff = (ct * 16 + frow) * HW2_K + fq * 8;
            s16x8 bh0 = *(s16x8*)&bhi[boff];
            s16x8 bh1 = *(s16x8*)&bhi[boff + 32];
            s16x8 bl0 = *(s16x8*)&blo[boff];
            s16x8 bl1 = *(s16x8*)&blo[boff + 32];
            acc[rt][ct] = __builtin_amdgcn_mfma_f32_16x16x32_bf16(ah0, bh0, acc[rt][ct], 0, 0, 0);
            acc[rt][ct] = __builtin_amdgcn_mfma_f32_16x16x32_bf16(ah1, bh1, acc[rt][ct], 0, 0, 0);
            acc[rt][ct] = __builtin_amdgcn_mfma_f32_16x16x32_bf16(ah0, bl0, acc[rt][ct], 0, 0, 0);
            acc[rt][ct] = __builtin_amdgcn_mfma_f32_16x16x32_bf16(ah1, bl1, acc[rt][ct], 0, 0, 0);
            acc[rt][ct] = __builtin_amdgcn_mfma_f32_16x16x32_bf16(al0, bh0, acc[rt][ct], 0, 0, 0);
            acc[rt][ct] = __builtin_amdgcn_mfma_f32_16x16x32_bf16(al1, bh1, acc[rt][ct], 0, 0, 0);
        }
    }
#pragma unroll
    for (int rt = 0; rt < 2; ++rt)
#pragma unroll
        for (int ct = 0; ct < 2; ++ct) {
            int col = ct * 16 + frow;
#pragma unroll
            for (int i = 0; i < 4; ++i) {
                int r = r0 + rt * 16 + fq * 4 + i;
                int g = nb + r;
                if (g < NN)
                    hw2[g * 32 + col] = __float2half_rn(acc[rt][ct][i] * sdin[r]);
            }
        }
}

// ---------------- layer-2 gather (R18: masked 16-deep, tail-free) ----------
__global__ __launch_bounds__(256) void k_gather2(const int* __restrict__ off,
                                                 const int* __restrict__ csr,
                                                 const float* __restrict__ dinv,
                                                 const __half* __restrict__ hw,
                                                 const float* __restrict__ b2,
                                                 const float* __restrict__ Wl,
                                                 float* __restrict__ outz,
                                                 float* __restrict__ uu,
                                                 float* __restrict__ vv) {
    int lane = threadIdx.x & 63;
    int half = lane >> 5;
    int j = lane & 31;
    int wave = threadIdx.x >> 6;
    int d = blockIdx.x * 4 + wave;             // grid = NN/4 exactly
    int start = (d == 0) ? 0 : off[d - 1];
    int end = off[d];
    start = __builtin_amdgcn_readfirstlane(start);
    end   = __builtin_amdgcn_readfirstlane(end);
    float dd = dinv[d];
    float hself = __half2float(hw[d * 32 + j]);      // hoisted
    float accA = 0.0f, accB = 0.0f, accC = 0.0f, accD = 0.0f;
    for (int e = start; e < end; e += 16) {
        int rem = end - e;                     // >= 1 (SGPR)
        int s0 = csr[e];                       // clamp target (uniform)
        int i1 = e + half;
        int sA = (half      < rem) ? csr[i1]      : s0;
        int sB = (half + 2  < rem) ? csr[i1 + 2]  : s0;
        int sC = (half + 4  < rem) ? csr[i1 + 4]  : s0;
        int sD = (half + 6  < rem) ? csr[i1 + 6]  : s0;
        int sE = (half + 8  < rem) ? csr[i1 + 8]  : s0;
        int sF = (half + 10 < rem) ? csr[i1 + 10] : s0;
        int sG = (half + 12 < rem) ? csr[i1 + 12] : s0;
        int sH = (half + 14 < rem) ? csr[i1 + 14] : s0;
        float gA = __half2float(hw[sA * 32 + j]);
        float gB = __half2float(hw[sB * 32 + j]);
        float gC = __half2float(hw[sC * 32 + j]);
        float gD = __half2float(hw[sD * 32 + j]);
        float gE = __half2float(hw[sE * 32 + j]);
        float gF = __half2float(hw[sF * 32 + j]);
        float gG = __half2float(hw[sG * 32 + j]);
        float gH = __half2float(hw[sH * 32 + j]);
        int nv = (rem - half + 1) >> 1;        // valid slots this half
        if (nv > 8) nv = 8;
        int inv = 8 - nv;                      // clamped slots this half
        accA += gA; accB += gB; accC += gC; accD += gD;
        accA += gE; accB += gF; accC += gG; accD += gH;
        accD = fmaf(-(float)inv, gH, accD);    // gH == r0 whenever inv > 0
    }
    float acc = (accA + accB) + (accC + accD);
    acc += __shfl(acc, lane ^ 32, 64);         // combine halves (full exec)
    float z = b2[j] + dd * (acc + hself);      // valid on all lanes
    if (half == 0)
        outz[d * 32 + j] = z;
    // per-node link-pred dots (all lanes; halves compute identical values)
    float p0 = z * Wl[j];
    float p1 = z * Wl[32 + j];
    p0 += __shfl_xor(p0, 1, 64);  p1 += __shfl_xor(p1, 1, 64);
    p0 += __shfl_xor(p0, 2, 64);  p1 += __shfl_xor(p1, 2, 64);
    p0 += __shfl_xor(p0, 4, 64);  p1 += __shfl_xor(p1, 4, 64);
    p0 += __shfl_xor(p0, 8, 64);  p1 += __shfl_xor(p1, 8, 64);
    p0 += __shfl_xor(p0, 16, 64); p1 += __shfl_xor(p1, 16, 64);
    if (lane == 0) { uu[d] = p0; vv[d] = p1; }
}

// ---------------- link prediction head: pred = u[s] + v[d] + bl ------------
__global__ __launch_bounds__(256) void k_linkpred(const int* __restrict__ sidx,
                                                  const int* __restrict__ didx,
                                                  const float* __restrict__ uu,
                                                  const float* __restrict__ vv,
                                                  const float* __restrict__ bl,
                                                  float* __restrict__ pred) {
    int e = blockIdx.x * 256 + threadIdx.x;
    if (e < NEL)
        pred[e] = uu[sidx[e]] + vv[didx[e]] + bl[0];
}

extern "C" void kernel_launch(void* const* d_in, const int* in_sizes, int n_in,
                              void* d_out, int out_size, void* d_ws, size_t ws_size,
                              hipStream_t stream) {
    const float* x    = (const float*)d_in[0];
    const float* pos  = (const float*)d_in[1];
    const float* W1   = (const float*)d_in[2];
    const float* b1   = (const float*)d_in[3];
    const float* W2   = (const float*)d_in[4];
    const float* b2   = (const float*)d_in[5];
    const float* Wl   = (const float*)d_in[6];
    const float* bl   = (const float*)d_in[7];
    const int*   ei   = (const int*)d_in[8];   // [2, NE]
    const int*   eli  = (const int*)d_in[9];   // [2, NEL]
    const int* src  = ei;
    const int* dst  = ei + NE;
    const int* lsrc = eli;
    const int* ldst = eli + NEL;

    float* out_z    = (float*)d_out;            // [NN, 32]
    float* out_pred = (float*)d_out + NN * 32;  // [NEL]

    // workspace: dinv[NN]f | off[NN]i | gcur[NBUCK] | csr[NE]i |
    //            hw1'[NN*64]h (aliases part[NBUCK*CAPB]i = 8.0 MB, dead after
    //            k_build; also provides safe slack for the <=15-int csr
    //            over-reads in the masked gather loops) | h2[NN*64]h (dead
    //            after k_hw2 -> reused for uu/vv) | hw2'[NN*32]h  ~= 39.2 MB
    float*  dinv  = (float*)d_ws;
    int*    off   = (int*)(dinv + NN);
    int*    gcur  = off + NN;
    int*    csr   = gcur + NBUCK;
    __half* hw1   = (__half*)(csr + NE);
    int*    part  = (int*)hw1;                  // 8.0 MB <= hw1's 12.8 MB
    __half* h2    = hw1 + NN * 64;
    __half* hw2   = h2 + NN * 64;
    float*  uu    = (float*)h2;                 // h2 dead after k_hw2
    float*  vv    = uu + NN;

    // 1) CSR build: partition -> per-bucket LDS sort (prefix fused, +dinv)
    hipMemsetAsync(gcur, 0, NBUCK * sizeof(int), stream);
    k_part<<<(NE + TPE - 1) / TPE, 256, 0, stream>>>(src, dst, gcur, part);
    k_build<<<NBUCK, 256, 0, stream>>>(gcur, part, csr, off, dinv);

    // 2) hw1' = dinv * ([x|pos] @ W1), MFMA bf16-split (part now dead)
    k_hw1<<<(NN + 63) / 64, 256, 0, stream>>>(x, pos, W1, dinv, hw1);

    // 3) layer-1 gather + bias + relu -> h2 (fp16), masked 16-deep
    k_gather1<<<NN / 4, 256, 0, stream>>>(off, csr, dinv, hw1, b1, h2);

    // 4) hw2' = dinv * (h2 @ W2), MFMA bf16-split
    k_hw2<<<(NN + 127) / 128, 256, 0, stream>>>(h2, W2, dinv, hw2);

    // 5) layer-2 gather + bias -> z (fp32 out) + per-node linkpred dots u,v
    k_gather2<<<NN / 4, 256, 0, stream>>>(off, csr, dinv, hw2, b2, Wl,
                                          out_z, uu, vv);

    // 6) link prediction: pred[e] = u[s] + v[d] + bl
    k_linkpred<<<(NEL + 255) / 256, 256, 0, stream>>>(lsrc, ldst, uu, vv, bl,
                                                      out_pred);
}